// Round 1
// baseline (1293.906 us; speedup 1.0000x reference)
//
#include <hip/hip_runtime.h>
#include <hip/hip_bf16.h>

#define B_   2048
#define L_   200
#define H_   128
#define SCALE_ 5000000.0f

typedef __attribute__((ext_vector_type(8))) short bf16x8;  // 8 bf16 = 4 VGPR
typedef __attribute__((ext_vector_type(4))) float f32x4;   // MFMA acc

__device__ __forceinline__ short to_bf16(float f) {
    __hip_bfloat16 h = __float2bfloat16(f);
    return *reinterpret_cast<short*>(&h);
}
__device__ __forceinline__ float fsig(float x) {
    // 1/(1+e^-x) = rcp(1 + 2^(-x*log2e))
    return __builtin_amdgcn_rcpf(1.0f + __builtin_amdgcn_exp2f(-1.442695041f * x));
}
__device__ __forceinline__ float ftanh(float x) {
    // tanh = 1 - 2/(e^{2x}+1)
    return 1.0f - 2.0f * __builtin_amdgcn_rcpf(1.0f + __builtin_amdgcn_exp2f(2.885390082f * x));
}

// ---------------------------------------------------------------------------
// Prep: pack weights into bf16 MFMA B-fragment order, fold biases.
// B-frag (16x16x32): lane l holds B[n=16-col][k], n = (l&15)+16*tile,
// k = kt*32 + (l>>4)*8 + b, b=0..7.
// ufrag flat: ((w*4+g)*8+kt)*64*8 ; wfrag: ((w*4+g)*4+kt)*64*8 ; wd: ((w*4+kt))*64*8
// ---------------------------------------------------------------------------
__global__ void prep_kernel(const float* __restrict__ U_all, const float* __restrict__ W_all,
                            const float* __restrict__ W_d, const float* __restrict__ b_W,
                            const float* __restrict__ b_U, const float* __restrict__ b_d,
                            short* __restrict__ ufrag, short* __restrict__ wfrag,
                            short* __restrict__ wdfrag, float* __restrict__ bias512,
                            float* __restrict__ bdo) {
    int i = blockIdx.x * 256 + threadIdx.x;
    if (i < 131072) {                     // U_all [512][256]
        int b = i & 7, lane = (i >> 3) & 63, kt = (i >> 9) & 7, g = (i >> 12) & 3, w = i >> 14;
        int n = g * 128 + w * 16 + (lane & 15);
        int k = kt * 32 + (lane >> 4) * 8 + b;
        ufrag[i] = to_bf16(U_all[n * 256 + k]);
    } else if (i < 196608) {              // W_all [512][128]
        int j = i - 131072;
        int b = j & 7, lane = (j >> 3) & 63, kt = (j >> 9) & 3, g = (j >> 11) & 3, w = j >> 13;
        int n = g * 128 + w * 16 + (lane & 15);
        int k = kt * 32 + (lane >> 4) * 8 + b;
        wfrag[j] = to_bf16(W_all[n * 128 + k]);
    } else if (i < 212992) {              // W_d [128][128]
        int m = i - 196608;
        int b = m & 7, lane = (m >> 3) & 63, kt = (m >> 9) & 3, w = m >> 11;
        int n = w * 16 + (lane & 15);
        int k = kt * 32 + (lane >> 4) * 8 + b;
        wdfrag[m] = to_bf16(W_d[n * 128 + k]);
    } else if (i < 213504) {
        int n = i - 212992;
        bias512[n] = b_W[n] + b_U[n];
    } else if (i < 213632) {
        int n = i - 213504;
        bdo[n] = b_d[n];
    }
}

// ---------------------------------------------------------------------------
// Fused TimeLSTM. 128 blocks x 512 thr (8 waves). Block owns 16 batch rows.
// Wave w: gate cols [16w,16w+16) of each gate f/i/o/g + c_s1 cols [16w,16w+16).
// Weights register-resident as B-frags; x_t via double-buffered LDS A-frags.
// ---------------------------------------------------------------------------
__global__ __launch_bounds__(512, 2) void lstm_kernel(
    const float* __restrict__ seq, const float* __restrict__ seq_e,
    const float* __restrict__ time_diff,
    const short* __restrict__ ufrag, const short* __restrict__ wfrag,
    const short* __restrict__ wdfrag, const float* __restrict__ bias512,
    const float* __restrict__ bdv, float* __restrict__ hn_buf) {

    __shared__ __align__(16) short xfrag[2][8][512];   // [buf][ktile][lane*8] 16 KB
    __shared__ __align__(16) short hS[16 * 136];       // h bf16, row-major pad 136
    __shared__ __align__(16) short cS[16 * 136];       // c bf16
    __shared__ float tspan[16 * 201];                  // per-row time spans

    const int tid   = threadIdx.x;
    const int w     = tid >> 6;      // wave 0..7
    const int lane  = tid & 63;
    const int col16 = lane & 15;     // MFMA n / C-col index
    const int quad  = lane >> 4;     // 0..3
    const int row0  = quad * 4;      // C-layout rows row0..row0+3
    const int b0    = blockIdx.x * 16;

    // --- persistent weight fragments (208 VGPR) ---
    bf16x8 uB[4][8], wB[4][4], wd[4];
#pragma unroll
    for (int g = 0; g < 4; ++g)
#pragma unroll
        for (int kt = 0; kt < 8; ++kt)
            uB[g][kt] = ((const bf16x8*)ufrag)[((w * 4 + g) * 8 + kt) * 64 + lane];
#pragma unroll
    for (int g = 0; g < 4; ++g)
#pragma unroll
        for (int kt = 0; kt < 4; ++kt)
            wB[g][kt] = ((const bf16x8*)wfrag)[((w * 4 + g) * 4 + kt) * 64 + lane];
#pragma unroll
    for (int kt = 0; kt < 4; ++kt)
        wd[kt] = ((const bf16x8*)wdfrag)[(w * 4 + kt) * 64 + lane];

    float bs[4];
#pragma unroll
    for (int g = 0; g < 4; ++g) bs[g] = bias512[g * 128 + w * 16 + col16];
    const float bd = bdv[w * 16 + col16];

    // --- time spans: tspan[r][t] = (td[t-1]-td[t])/SCALE, 0 at t=0 ---
    for (int i = tid; i < 16 * L_; i += 512) {
        int r = i / L_, t = i - r * L_;
        float v = 0.0f;
        if (t > 0) {
            const float* td = time_diff + (size_t)(b0 + r) * L_;
            v = (td[t - 1] - td[t]) * (1.0f / SCALE_);
        }
        tspan[r * 201 + t] = v;
    }
    for (int i = tid; i < 16 * 136; i += 512) { hS[i] = 0; cS[i] = 0; }

    // --- x staging role: this thread loads row=col16, k in [kb, kb+8) ---
    const int kb = w * 32 + quad * 8;  // 0..255 : <128 from seq, else seq_e
    const float* xsrc = (kb < 128)
        ? (seq   + (size_t)(b0 + col16) * L_ * 128 + kb)
        : (seq_e + (size_t)(b0 + col16) * L_ * 128 + (kb - 128));

    {   // stage t = 0 into buffer 0
        const float4* p = (const float4*)xsrc;
        float4 a0 = p[0], a1 = p[1];
        bf16x8 sv;
        sv[0] = to_bf16(a0.x); sv[1] = to_bf16(a0.y); sv[2] = to_bf16(a0.z); sv[3] = to_bf16(a0.w);
        sv[4] = to_bf16(a1.x); sv[5] = to_bf16(a1.y); sv[6] = to_bf16(a1.z); sv[7] = to_bf16(a1.w);
        ((bf16x8*)xfrag[0][w])[lane] = sv;
    }
    __syncthreads();

    f32x4 cacc = {0.f, 0.f, 0.f, 0.f};   // persistent c (fp32), col 16w+col16
    float hreg[4] = {0.f, 0.f, 0.f, 0.f};
    int par = 0;

    for (int t = 0; t < L_; ++t) {
        // prefetch x_{t+1} (clamped; last iter's store is unused)
        int tt = (t + 1 < L_) ? (t + 1) : (L_ - 1);
        const float4* p = (const float4*)(xsrc + (size_t)tt * 128);
        float4 a0 = p[0], a1 = p[1];

        // gates = bias + x_t @ U^T + h @ W^T   (acc in C-layout)
        f32x4 acc[4];
#pragma unroll
        for (int g = 0; g < 4; ++g) acc[g] = (f32x4){bs[g], bs[g], bs[g], bs[g]};
#pragma unroll
        for (int kt = 0; kt < 8; ++kt) {
            bf16x8 a = ((const bf16x8*)xfrag[par][kt])[lane];
#pragma unroll
            for (int g = 0; g < 4; ++g)
                acc[g] = __builtin_amdgcn_mfma_f32_16x16x32_bf16(a, uB[g][kt], acc[g], 0, 0, 0);
        }
#pragma unroll
        for (int kt = 0; kt < 4; ++kt) {
            bf16x8 a = *(const bf16x8*)&hS[col16 * 136 + kt * 32 + quad * 8];
#pragma unroll
            for (int g = 0; g < 4; ++g)
                acc[g] = __builtin_amdgcn_mfma_f32_16x16x32_bf16(a, wB[g][kt], acc[g], 0, 0, 0);
        }
        // c_s1 pre-activation = c @ W_d^T + b_d
        f32x4 cs = {bd, bd, bd, bd};
#pragma unroll
        for (int kt = 0; kt < 4; ++kt) {
            bf16x8 a = *(const bf16x8*)&cS[col16 * 136 + kt * 32 + quad * 8];
            cs = __builtin_amdgcn_mfma_f32_16x16x32_bf16(a, wd[kt], cs, 0, 0, 0);
        }
        __syncthreads();   // all LDS reads of hS/cS done before overwrite

        // elementwise TimeLSTM update, fully in-register
#pragma unroll
        for (int r = 0; r < 4; ++r) {
            float ttv = tspan[(row0 + r) * 201 + t];
            float f   = fsig(acc[0][r]);
            float i_  = fsig(acc[1][r]);
            float o   = fsig(acc[2][r]);
            float g4  = fsig(acc[3][r]);   // note: reference uses sigmoid for g
            float cs1 = ftanh(cs[r]);
            float ca  = cacc[r] - cs1 + cs1 * ttv;
            float cn  = f * ca + i_ * g4;
            float hv  = o * ftanh(cn);
            cacc[r] = cn;
            hreg[r] = hv;
            hS[(row0 + r) * 136 + w * 16 + col16] = to_bf16(hv);
            cS[(row0 + r) * 136 + w * 16 + col16] = to_bf16(cn);
        }
        {   // stage prefetched x into the other buffer
            bf16x8 sv;
            sv[0] = to_bf16(a0.x); sv[1] = to_bf16(a0.y); sv[2] = to_bf16(a0.z); sv[3] = to_bf16(a0.w);
            sv[4] = to_bf16(a1.x); sv[5] = to_bf16(a1.y); sv[6] = to_bf16(a1.z); sv[7] = to_bf16(a1.w);
            ((bf16x8*)xfrag[par ^ 1][w])[lane] = sv;
        }
        par ^= 1;
        __syncthreads();
    }

    // final h_n (fp32) -> hn_buf (= d_out used as scratch)
#pragma unroll
    for (int r = 0; r < 4; ++r)
        hn_buf[(size_t)(b0 + row0 + r) * 128 + w * 16 + col16] = hreg[r];
}

// ---------------------------------------------------------------------------
// Merge: out = fc2( relu( fc1( [hn, src] ) ) ), in-place over d_out.
// Block handles 16 rows; reads its rows to LDS before overwriting them.
// ---------------------------------------------------------------------------
__global__ __launch_bounds__(256) void merge_kernel(
    const float* __restrict__ src, const float* __restrict__ fc1w,
    const float* __restrict__ fc1b, const float* __restrict__ fc2w,
    const float* __restrict__ fc2b, float* __restrict__ out) {
    __shared__ float xc[16][256];
    __shared__ float hm[16][128];
    const int tid = threadIdx.x;
    const int b0  = blockIdx.x * 16;
    for (int i = tid; i < 16 * 256; i += 256) {
        int r = i >> 8, k = i & 255;
        xc[r][k] = (k < 128) ? out[(size_t)(b0 + r) * 128 + k]
                             : src[(size_t)(b0 + r) * 128 + (k - 128)];
    }
    __syncthreads();
#pragma unroll
    for (int ii = 0; ii < 8; ++ii) {
        int o = tid + 256 * ii;
        int r = o >> 7, m = o & 127;
        const float4* wr = (const float4*)(fc1w + m * 256);
        const float4* xr = (const float4*)(xc[r]);
        float acc = fc1b[m];
        for (int k4 = 0; k4 < 64; ++k4) {
            float4 a = wr[k4], b = xr[k4];
            acc += a.x * b.x + a.y * b.y + a.z * b.z + a.w * b.w;
        }
        hm[r][m] = fmaxf(acc, 0.0f);
    }
    __syncthreads();
#pragma unroll
    for (int ii = 0; ii < 8; ++ii) {
        int o = tid + 256 * ii;
        int r = o >> 7, j = o & 127;
        const float4* wr = (const float4*)(fc2w + j * 128);
        const float4* xr = (const float4*)(hm[r]);
        float acc = fc2b[j];
        for (int k4 = 0; k4 < 32; ++k4) {
            float4 a = wr[k4], b = xr[k4];
            acc += a.x * b.x + a.y * b.y + a.z * b.z + a.w * b.w;
        }
        out[(size_t)(b0 + r) * 128 + j] = acc;
    }
}

// ---------------------------------------------------------------------------
extern "C" void kernel_launch(void* const* d_in, const int* in_sizes, int n_in,
                              void* d_out, int out_size, void* d_ws, size_t ws_size,
                              hipStream_t stream) {
    const float* src       = (const float*)d_in[0];
    // d_in[1] src_t : unused
    const float* seq       = (const float*)d_in[2];
    // d_in[3] seq_t : unused
    const float* seq_e     = (const float*)d_in[4];
    const float* time_diff = (const float*)d_in[5];
    // d_in[6] mask : unused
    const float* W_all     = (const float*)d_in[7];
    const float* b_W       = (const float*)d_in[8];
    const float* U_all     = (const float*)d_in[9];
    const float* b_U       = (const float*)d_in[10];
    const float* W_d       = (const float*)d_in[11];
    const float* b_d       = (const float*)d_in[12];
    const float* fc1w      = (const float*)d_in[13];
    const float* fc1b      = (const float*)d_in[14];
    const float* fc2w      = (const float*)d_in[15];
    const float* fc2b      = (const float*)d_in[16];

    char* ws = (char*)d_ws;
    short* ufrag   = (short*)(ws);            // 262144 B
    short* wfrag   = (short*)(ws + 262144);   // 131072 B
    short* wdfrag  = (short*)(ws + 393216);   //  32768 B
    float* bias512 = (float*)(ws + 425984);   //   2048 B
    float* bdo     = (float*)(ws + 428032);   //    512 B
    float* outp    = (float*)d_out;           // also hn scratch (merge is in-place safe)

    prep_kernel<<<835, 256, 0, stream>>>(U_all, W_all, W_d, b_W, b_U, b_d,
                                         ufrag, wfrag, wdfrag, bias512, bdo);
    lstm_kernel<<<128, 512, 0, stream>>>(seq, seq_e, time_diff,
                                         ufrag, wfrag, wdfrag, bias512, bdo, outp);
    merge_kernel<<<128, 256, 0, stream>>>(src, fc1w, fc1b, fc2w, fc2b, outp);
}

// Round 2
// 1009.195 us; speedup vs baseline: 1.2821x; 1.2821x over previous
//
#include <hip/hip_runtime.h>
#include <hip/hip_bf16.h>
#include <stdint.h>

#define L_ 200
#define SCALE_ 5000000.0f

typedef __attribute__((ext_vector_type(8))) short bf16x8;  // 8 bf16 = 4 VGPR
typedef __attribute__((ext_vector_type(4))) float f32x4;   // MFMA acc

static __device__ __forceinline__ short to_bf16(float f) {
    __hip_bfloat16 h = __float2bfloat16(f);
    return *reinterpret_cast<short*>(&h);
}
static __device__ __forceinline__ float fsig(float x) {
    return __builtin_amdgcn_rcpf(1.0f + __builtin_amdgcn_exp2f(-1.442695041f * x));
}
static __device__ __forceinline__ float ftanh(float x) {
    return 1.0f - 2.0f * __builtin_amdgcn_rcpf(1.0f + __builtin_amdgcn_exp2f(2.885390082f * x));
}
static __device__ __forceinline__ float bf_lo(unsigned p) {  // lower short -> f32
    union { unsigned u; float f; } c; c.u = p << 16; return c.f;
}
static __device__ __forceinline__ float bf_hi(unsigned p) {  // upper short -> f32
    union { unsigned u; float f; } c; c.u = p & 0xffff0000u; return c.f;
}

// ---------------------------------------------------------------------------
// Prep: pack weights into bf16 MFMA B-fragment order, fold biases, and
// (split path) precompute time spans tsw[g][l][16] fp32.
// B-frag (16x16x32): lane l holds B[n][k], n=(l&15)+16*tile, k=kt*32+(l>>4)*8+b.
// ---------------------------------------------------------------------------
__global__ void prep_kernel(const float* __restrict__ U_all, const float* __restrict__ W_all,
                            const float* __restrict__ W_d, const float* __restrict__ b_W,
                            const float* __restrict__ b_U, const float* __restrict__ b_d,
                            const float* __restrict__ time_diff,
                            short* __restrict__ ufrag, short* __restrict__ wfrag,
                            short* __restrict__ wdfrag, float* __restrict__ bias512,
                            float* __restrict__ bdo, float* __restrict__ tsw,
                            int n_total) {
    int i = blockIdx.x * 256 + threadIdx.x;
    if (i >= n_total) return;
    if (i < 131072) {                     // U_all [512][256]
        int b = i & 7, lane = (i >> 3) & 63, kt = (i >> 9) & 7, g = (i >> 12) & 3, w = i >> 14;
        int n = g * 128 + w * 16 + (lane & 15);
        int k = kt * 32 + (lane >> 4) * 8 + b;
        ufrag[i] = to_bf16(U_all[n * 256 + k]);
    } else if (i < 196608) {              // W_all [512][128]
        int j = i - 131072;
        int b = j & 7, lane = (j >> 3) & 63, kt = (j >> 9) & 3, g = (j >> 11) & 3, w = j >> 13;
        int n = g * 128 + w * 16 + (lane & 15);
        int k = kt * 32 + (lane >> 4) * 8 + b;
        wfrag[j] = to_bf16(W_all[n * 128 + k]);
    } else if (i < 212992) {              // W_d [128][128]
        int m = i - 196608;
        int b = m & 7, lane = (m >> 3) & 63, kt = (m >> 9) & 3, w = m >> 11;
        int n = w * 16 + (lane & 15);
        int k = kt * 32 + (lane >> 4) * 8 + b;
        wdfrag[m] = to_bf16(W_d[n * 128 + k]);
    } else if (i < 213504) {
        int n = i - 212992;
        bias512[n] = b_W[n] + b_U[n];
    } else if (i < 213632) {
        int n = i - 213504;
        bdo[n] = b_d[n];
    } else {                              // tsw[g][l][16]
        int j = i - 213632;               // (g*200+l)*16 + m
        int m = j & 15, rest = j >> 4;
        int l = rest % 200, g = rest / 200;
        float v = 0.0f;
        if (l > 0) {
            const float* td = time_diff + (size_t)(g * 16 + m) * L_;
            v = (td[l - 1] - td[l]) * (1.0f / SCALE_);
        }
        tsw[j] = v;
    }
}

// ---------------------------------------------------------------------------
// ugemm: u[g][l][n][16] (bf16) = x[b][l][0:256] @ U_all^T   (no bias)
// Block = 32 M-rows (2 l's x 16 batch of one group) x full N=512. 8 waves,
// each wave owns a 64-col N-slice with register-resident B-frags.
// Grid = 128 groups x 100 l-tiles = 12800.
// ---------------------------------------------------------------------------
__global__ __launch_bounds__(512, 2) void ugemm_kernel(
    const float* __restrict__ seq, const float* __restrict__ seq_e,
    const short* __restrict__ ufrag, short* __restrict__ uws) {
    __shared__ __align__(16) short aF[8192];   // 2 mtiles x 8 kt x 512 shorts (16 KB)

    const int tid = threadIdx.x;
    const int w = tid >> 6, lane = tid & 63;
    const int col16 = lane & 15, quad = lane >> 4;
    const int bid = blockIdx.x;
    const int g = bid & 127, lt = bid >> 7;    // lt 0..99

    // stage A tile 32x256 fp32 -> bf16 frags
#pragma unroll
    for (int rep = 0; rep < 2; ++rep) {
        int id = rep * 512 + tid;              // 0..1023
        int c = id & 31, m = id >> 5;          // chunk, row
        int brow = m & 15, lloc = m >> 4;
        int k = c * 8;
        const float* srcp = (k < 128)
            ? seq   + ((size_t)(g * 16 + brow) * L_ + lt * 2 + lloc) * 128 + k
            : seq_e + ((size_t)(g * 16 + brow) * L_ + lt * 2 + lloc) * 128 + (k - 128);
        float4 p0 = ((const float4*)srcp)[0], p1 = ((const float4*)srcp)[1];
        bf16x8 sv;
        sv[0] = to_bf16(p0.x); sv[1] = to_bf16(p0.y); sv[2] = to_bf16(p0.z); sv[3] = to_bf16(p0.w);
        sv[4] = to_bf16(p1.x); sv[5] = to_bf16(p1.y); sv[6] = to_bf16(p1.z); sv[7] = to_bf16(p1.w);
        ((bf16x8*)aF)[(lloc * 8 + (c >> 2)) * 64 + (c & 3) * 16 + brow] = sv;
    }

    // register-resident B frags for this wave's 64-col slice
    bf16x8 Bf[4][8];
#pragma unroll
    for (int j = 0; j < 4; ++j) {
        int nt = w * 4 + j, gg = nt >> 3, ww = nt & 7;
#pragma unroll
        for (int kt = 0; kt < 8; ++kt)
            Bf[j][kt] = ((const bf16x8*)ufrag)[(((ww * 4 + gg) * 8) + kt) * 64 + lane];
    }

    f32x4 acc[2][4];
#pragma unroll
    for (int mt = 0; mt < 2; ++mt)
#pragma unroll
        for (int j = 0; j < 4; ++j) acc[mt][j] = (f32x4){0.f, 0.f, 0.f, 0.f};

    __syncthreads();

#pragma unroll
    for (int kt = 0; kt < 8; ++kt) {
        bf16x8 a0 = ((const bf16x8*)aF)[(0 * 8 + kt) * 64 + lane];
        bf16x8 a1 = ((const bf16x8*)aF)[(1 * 8 + kt) * 64 + lane];
#pragma unroll
        for (int j = 0; j < 4; ++j) {
            acc[0][j] = __builtin_amdgcn_mfma_f32_16x16x32_bf16(a0, Bf[j][kt], acc[0][j], 0, 0, 0);
            acc[1][j] = __builtin_amdgcn_mfma_f32_16x16x32_bf16(a1, Bf[j][kt], acc[1][j], 0, 0, 0);
        }
    }

    // store: u[((g*200+l)*512+n)*16 + brow], brow = quad*4+r (4 shorts -> uint2)
#pragma unroll
    for (int mt = 0; mt < 2; ++mt)
#pragma unroll
        for (int j = 0; j < 4; ++j) {
            int n = (w * 4 + j) * 16 + col16;
            size_t base = (((size_t)g * L_ + lt * 2 + mt) * 512 + n) * 16 + quad * 4;
            unsigned lo = (unsigned short)to_bf16(acc[mt][j][0])
                        | ((unsigned)(unsigned short)to_bf16(acc[mt][j][1]) << 16);
            unsigned hi = (unsigned short)to_bf16(acc[mt][j][2])
                        | ((unsigned)(unsigned short)to_bf16(acc[mt][j][3]) << 16);
            uint2 v; v.x = lo; v.y = hi;
            *(uint2*)(uws + base) = v;
        }
}

// ---------------------------------------------------------------------------
// Recurrent TimeLSTM (u precomputed). 128 blocks x 512 thr (8 waves),
// block = 16 batch rows. h/c kept as bf16 A-frags in double-buffered LDS;
// ONE barrier per step. u_t and tspan prefetched from global 1 step ahead.
// ---------------------------------------------------------------------------
__global__ __launch_bounds__(512, 2) void rec_kernel(
    const short* __restrict__ uws, const short* __restrict__ wfrag,
    const short* __restrict__ wdfrag, const float* __restrict__ bias512,
    const float* __restrict__ bdv, const float* __restrict__ tsw,
    float* __restrict__ hn_buf) {

    __shared__ __align__(16) short hf[2][2048];   // A-frag layout, 4 kt x 512
    __shared__ __align__(16) short cf[2][2048];

    const int tid = threadIdx.x;
    const int w = tid >> 6, lane = tid & 63;
    const int col16 = lane & 15, quad = lane >> 4;
    const int g = blockIdx.x;

    bf16x8 wB[4][4], wd[4];
#pragma unroll
    for (int gg = 0; gg < 4; ++gg)
#pragma unroll
        for (int kt = 0; kt < 4; ++kt)
            wB[gg][kt] = ((const bf16x8*)wfrag)[((w * 4 + gg) * 4 + kt) * 64 + lane];
#pragma unroll
    for (int kt = 0; kt < 4; ++kt)
        wd[kt] = ((const bf16x8*)wdfrag)[(w * 4 + kt) * 64 + lane];

    float bs[4];
#pragma unroll
    for (int gg = 0; gg < 4; ++gg) bs[gg] = bias512[gg * 128 + w * 16 + col16];
    const float bd = bdv[w * 16 + col16];

    for (int i = tid; i < 2048; i += 512) {
        hf[0][i] = 0; hf[1][i] = 0; cf[0][i] = 0; cf[1][i] = 0;
    }

    // write offset: element (row, col=w*16+col16) in A-frag layout
    const int kto = (w >> 1) * 512 + ((w & 1) * 2 + (col16 >> 3)) * 128 + (col16 & 7);

    // prefetch t=0
    uint2 ucur[4], unxt[4];
#pragma unroll
    for (int gg = 0; gg < 4; ++gg)
        ucur[gg] = *(const uint2*)(uws + (((size_t)g * L_ + 0) * 512 + gg * 128 + w * 16 + col16) * 16 + quad * 4);
    float4 tcur = *(const float4*)(tsw + ((size_t)g * L_ + 0) * 16 + quad * 4);
    float4 tnxt;

    __syncthreads();

    f32x4 cacc = {0.f, 0.f, 0.f, 0.f};
    float hreg[4] = {0.f, 0.f, 0.f, 0.f};
    int par = 0;

    for (int t = 0; t < L_; ++t) {
        int tp = (t + 1 < L_) ? t + 1 : L_ - 1;
#pragma unroll
        for (int gg = 0; gg < 4; ++gg)
            unxt[gg] = *(const uint2*)(uws + (((size_t)g * L_ + tp) * 512 + gg * 128 + w * 16 + col16) * 16 + quad * 4);
        tnxt = *(const float4*)(tsw + ((size_t)g * L_ + tp) * 16 + quad * 4);

        // gates = bias + u_t + h @ W^T
        f32x4 acc[4];
#pragma unroll
        for (int gg = 0; gg < 4; ++gg) {
            acc[gg][0] = bs[gg] + bf_lo(ucur[gg].x);
            acc[gg][1] = bs[gg] + bf_hi(ucur[gg].x);
            acc[gg][2] = bs[gg] + bf_lo(ucur[gg].y);
            acc[gg][3] = bs[gg] + bf_hi(ucur[gg].y);
        }
#pragma unroll
        for (int kt = 0; kt < 4; ++kt) {
            bf16x8 a = ((const bf16x8*)hf[par])[kt * 64 + lane];
#pragma unroll
            for (int gg = 0; gg < 4; ++gg)
                acc[gg] = __builtin_amdgcn_mfma_f32_16x16x32_bf16(a, wB[gg][kt], acc[gg], 0, 0, 0);
        }
        f32x4 cs = {bd, bd, bd, bd};
#pragma unroll
        for (int kt = 0; kt < 4; ++kt) {
            bf16x8 a = ((const bf16x8*)cf[par])[kt * 64 + lane];
            cs = __builtin_amdgcn_mfma_f32_16x16x32_bf16(a, wd[kt], cs, 0, 0, 0);
        }

#pragma unroll
        for (int r = 0; r < 4; ++r) {
            float ttv = (r == 0) ? tcur.x : (r == 1) ? tcur.y : (r == 2) ? tcur.z : tcur.w;
            float f   = fsig(acc[0][r]);
            float i_  = fsig(acc[1][r]);
            float o   = fsig(acc[2][r]);
            float g4  = fsig(acc[3][r]);
            float cs1 = ftanh(cs[r]);
            float ca  = cacc[r] - cs1 + cs1 * ttv;
            float cn  = f * ca + i_ * g4;
            float hv  = o * ftanh(cn);
            cacc[r] = cn;
            hreg[r] = hv;
            hf[par ^ 1][kto + (quad * 4 + r) * 8] = to_bf16(hv);
            cf[par ^ 1][kto + (quad * 4 + r) * 8] = to_bf16(cn);
        }
        __syncthreads();
#pragma unroll
        for (int gg = 0; gg < 4; ++gg) ucur[gg] = unxt[gg];
        tcur = tnxt;
        par ^= 1;
    }

#pragma unroll
    for (int r = 0; r < 4; ++r)
        hn_buf[(size_t)(g * 16 + quad * 4 + r) * 128 + w * 16 + col16] = hreg[r];
}

// ---------------------------------------------------------------------------
// Fallback fused TimeLSTM (round-0 kernel) for small ws_size.
// ---------------------------------------------------------------------------
__global__ __launch_bounds__(512, 2) void lstm_kernel(
    const float* __restrict__ seq, const float* __restrict__ seq_e,
    const float* __restrict__ time_diff,
    const short* __restrict__ ufrag, const short* __restrict__ wfrag,
    const short* __restrict__ wdfrag, const float* __restrict__ bias512,
    const float* __restrict__ bdv, float* __restrict__ hn_buf) {

    __shared__ __align__(16) short xfrag[2][8][512];
    __shared__ __align__(16) short hS[16 * 136];
    __shared__ __align__(16) short cS[16 * 136];
    __shared__ float tspan[16 * 201];

    const int tid = threadIdx.x;
    const int w = tid >> 6, lane = tid & 63;
    const int col16 = lane & 15, quad = lane >> 4;
    const int row0 = quad * 4;
    const int b0 = blockIdx.x * 16;

    bf16x8 uB[4][8], wB[4][4], wd[4];
#pragma unroll
    for (int g = 0; g < 4; ++g)
#pragma unroll
        for (int kt = 0; kt < 8; ++kt)
            uB[g][kt] = ((const bf16x8*)ufrag)[((w * 4 + g) * 8 + kt) * 64 + lane];
#pragma unroll
    for (int g = 0; g < 4; ++g)
#pragma unroll
        for (int kt = 0; kt < 4; ++kt)
            wB[g][kt] = ((const bf16x8*)wfrag)[((w * 4 + g) * 4 + kt) * 64 + lane];
#pragma unroll
    for (int kt = 0; kt < 4; ++kt)
        wd[kt] = ((const bf16x8*)wdfrag)[(w * 4 + kt) * 64 + lane];

    float bs[4];
#pragma unroll
    for (int g = 0; g < 4; ++g) bs[g] = bias512[g * 128 + w * 16 + col16];
    const float bd = bdv[w * 16 + col16];

    for (int i = tid; i < 16 * L_; i += 512) {
        int r = i / L_, t = i - r * L_;
        float v = 0.0f;
        if (t > 0) {
            const float* td = time_diff + (size_t)(b0 + r) * L_;
            v = (td[t - 1] - td[t]) * (1.0f / SCALE_);
        }
        tspan[r * 201 + t] = v;
    }
    for (int i = tid; i < 16 * 136; i += 512) { hS[i] = 0; cS[i] = 0; }

    const int kb = w * 32 + quad * 8;
    const float* xsrc = (kb < 128)
        ? (seq   + (size_t)(b0 + col16) * L_ * 128 + kb)
        : (seq_e + (size_t)(b0 + col16) * L_ * 128 + (kb - 128));

    {
        const float4* p = (const float4*)xsrc;
        float4 a0 = p[0], a1 = p[1];
        bf16x8 sv;
        sv[0] = to_bf16(a0.x); sv[1] = to_bf16(a0.y); sv[2] = to_bf16(a0.z); sv[3] = to_bf16(a0.w);
        sv[4] = to_bf16(a1.x); sv[5] = to_bf16(a1.y); sv[6] = to_bf16(a1.z); sv[7] = to_bf16(a1.w);
        ((bf16x8*)xfrag[0][w])[lane] = sv;
    }
    __syncthreads();

    f32x4 cacc = {0.f, 0.f, 0.f, 0.f};
    float hreg[4] = {0.f, 0.f, 0.f, 0.f};
    int par = 0;

    for (int t = 0; t < L_; ++t) {
        int tt = (t + 1 < L_) ? (t + 1) : (L_ - 1);
        const float4* p = (const float4*)(xsrc + (size_t)tt * 128);
        float4 a0 = p[0], a1 = p[1];

        f32x4 acc[4];
#pragma unroll
        for (int g = 0; g < 4; ++g) acc[g] = (f32x4){bs[g], bs[g], bs[g], bs[g]};
#pragma unroll
        for (int kt = 0; kt < 8; ++kt) {
            bf16x8 a = ((const bf16x8*)xfrag[par][kt])[lane];
#pragma unroll
            for (int g = 0; g < 4; ++g)
                acc[g] = __builtin_amdgcn_mfma_f32_16x16x32_bf16(a, uB[g][kt], acc[g], 0, 0, 0);
        }
#pragma unroll
        for (int kt = 0; kt < 4; ++kt) {
            bf16x8 a = *(const bf16x8*)&hS[col16 * 136 + kt * 32 + quad * 8];
#pragma unroll
            for (int g = 0; g < 4; ++g)
                acc[g] = __builtin_amdgcn_mfma_f32_16x16x32_bf16(a, wB[g][kt], acc[g], 0, 0, 0);
        }
        f32x4 cs = {bd, bd, bd, bd};
#pragma unroll
        for (int kt = 0; kt < 4; ++kt) {
            bf16x8 a = *(const bf16x8*)&cS[col16 * 136 + kt * 32 + quad * 8];
            cs = __builtin_amdgcn_mfma_f32_16x16x32_bf16(a, wd[kt], cs, 0, 0, 0);
        }
        __syncthreads();

#pragma unroll
        for (int r = 0; r < 4; ++r) {
            float ttv = tspan[(row0 + r) * 201 + t];
            float f   = fsig(acc[0][r]);
            float i_  = fsig(acc[1][r]);
            float o   = fsig(acc[2][r]);
            float g4  = fsig(acc[3][r]);
            float cs1 = ftanh(cs[r]);
            float ca  = cacc[r] - cs1 + cs1 * ttv;
            float cn  = f * ca + i_ * g4;
            float hv  = o * ftanh(cn);
            cacc[r] = cn;
            hreg[r] = hv;
            hS[(row0 + r) * 136 + w * 16 + col16] = to_bf16(hv);
            cS[(row0 + r) * 136 + w * 16 + col16] = to_bf16(cn);
        }
        {
            bf16x8 sv;
            sv[0] = to_bf16(a0.x); sv[1] = to_bf16(a0.y); sv[2] = to_bf16(a0.z); sv[3] = to_bf16(a0.w);
            sv[4] = to_bf16(a1.x); sv[5] = to_bf16(a1.y); sv[6] = to_bf16(a1.z); sv[7] = to_bf16(a1.w);
            ((bf16x8*)xfrag[par ^ 1][w])[lane] = sv;
        }
        par ^= 1;
        __syncthreads();
    }

#pragma unroll
    for (int r = 0; r < 4; ++r)
        hn_buf[(size_t)(b0 + row0 + r) * 128 + w * 16 + col16] = hreg[r];
}

// ---------------------------------------------------------------------------
// Merge: out = fc2( relu( fc1( [hn, src] ) ) ), in-place over d_out.
// ---------------------------------------------------------------------------
__global__ __launch_bounds__(256) void merge_kernel(
    const float* __restrict__ src, const float* __restrict__ fc1w,
    const float* __restrict__ fc1b, const float* __restrict__ fc2w,
    const float* __restrict__ fc2b, float* __restrict__ out) {
    __shared__ float xc[16][256];
    __shared__ float hm[16][128];
    const int tid = threadIdx.x;
    const int b0 = blockIdx.x * 16;
    for (int i = tid; i < 16 * 256; i += 256) {
        int r = i >> 8, k = i & 255;
        xc[r][k] = (k < 128) ? out[(size_t)(b0 + r) * 128 + k]
                             : src[(size_t)(b0 + r) * 128 + (k - 128)];
    }
    __syncthreads();
#pragma unroll
    for (int ii = 0; ii < 8; ++ii) {
        int o = tid + 256 * ii;
        int r = o >> 7, m = o & 127;
        const float4* wr = (const float4*)(fc1w + m * 256);
        const float4* xr = (const float4*)(xc[r]);
        float acc = fc1b[m];
        for (int k4 = 0; k4 < 64; ++k4) {
            float4 a = wr[k4], b = xr[k4];
            acc += a.x * b.x + a.y * b.y + a.z * b.z + a.w * b.w;
        }
        hm[r][m] = fmaxf(acc, 0.0f);
    }
    __syncthreads();
#pragma unroll
    for (int ii = 0; ii < 8; ++ii) {
        int o = tid + 256 * ii;
        int r = o >> 7, j = o & 127;
        const float4* wr = (const float4*)(fc2w + j * 128);
        const float4* xr = (const float4*)(hm[r]);
        float acc = fc2b[j];
        for (int k4 = 0; k4 < 32; ++k4) {
            float4 a = wr[k4], b = xr[k4];
            acc += a.x * b.x + a.y * b.y + a.z * b.z + a.w * b.w;
        }
        out[(size_t)(b0 + r) * 128 + j] = acc;
    }
}

// ---------------------------------------------------------------------------
extern "C" void kernel_launch(void* const* d_in, const int* in_sizes, int n_in,
                              void* d_out, int out_size, void* d_ws, size_t ws_size,
                              hipStream_t stream) {
    const float* src       = (const float*)d_in[0];
    const float* seq       = (const float*)d_in[2];
    const float* seq_e     = (const float*)d_in[4];
    const float* time_diff = (const float*)d_in[5];
    const float* W_all     = (const float*)d_in[7];
    const float* b_W       = (const float*)d_in[8];
    const float* U_all     = (const float*)d_in[9];
    const float* b_U       = (const float*)d_in[10];
    const float* W_d       = (const float*)d_in[11];
    const float* b_d       = (const float*)d_in[12];
    const float* fc1w      = (const float*)d_in[13];
    const float* fc1b      = (const float*)d_in[14];
    const float* fc2w      = (const float*)d_in[15];
    const float* fc2b      = (const float*)d_in[16];

    char* ws = (char*)d_ws;
    short* ufrag   = (short*)(ws);             // 262144 B
    short* wfrag   = (short*)(ws + 262144);    // 131072 B
    short* wdfrag  = (short*)(ws + 393216);    //  32768 B
    float* bias512 = (float*)(ws + 425984);    //   2048 B
    float* bdo     = (float*)(ws + 428032);    //    512 B
    float* tsw     = (float*)(ws + 430080);    // 1638400 B
    short* uws     = (short*)(ws + 2068480);   // 419430400 B
    float* outp    = (float*)d_out;

    const size_t NEED_SPLIT = 2068480ull + 419430400ull;
    const bool split = ws_size >= NEED_SPLIT;

    if (split) {
        prep_kernel<<<2435, 256, 0, stream>>>(U_all, W_all, W_d, b_W, b_U, b_d, time_diff,
                                              ufrag, wfrag, wdfrag, bias512, bdo, tsw, 623232);
        ugemm_kernel<<<12800, 512, 0, stream>>>(seq, seq_e, ufrag, uws);
        rec_kernel<<<128, 512, 0, stream>>>(uws, wfrag, wdfrag, bias512, bdo, tsw, outp);
    } else {
        prep_kernel<<<835, 256, 0, stream>>>(U_all, W_all, W_d, b_W, b_U, b_d, time_diff,
                                             ufrag, wfrag, wdfrag, bias512, bdo, tsw, 213632);
        lstm_kernel<<<128, 512, 0, stream>>>(seq, seq_e, time_diff,
                                             ufrag, wfrag, wdfrag, bias512, bdo, outp);
    }
    merge_kernel<<<128, 256, 0, stream>>>(src, fc1w, fc1b, fc2w, fc2b, outp);
}